// Round 5
// baseline (734.429 us; speedup 1.0000x reference)
//
#include <hip/hip_runtime.h>
#include <hip/hip_bf16.h>
#include <cmath>

typedef __hip_bfloat16 bf16;
typedef __attribute__((ext_vector_type(8))) short s16x8;
typedef __attribute__((ext_vector_type(4))) float f32x4;

#define B_   2
#define T_   2048
#define C_   2048
#define H_   16
#define HD_  128
#define RD_  64
#define QLR_ 1536
#define KLR_ 512
#define SCALE_ 0.07216878364870322f   // (128+64)^-0.5

static __device__ __forceinline__ float b2f(bf16 v){ return __bfloat162float(v); }
static __device__ __forceinline__ bf16  f2b(float v){ return __float2bfloat16(v); }
static __device__ __forceinline__ float us2f(unsigned short u){
    union { unsigned short s[2]; float f; } v; v.s[0]=0; v.s[1]=u; return v.f;
}
static __device__ __forceinline__ float ldS(const void* p, size_t i, int isf32){
    return isf32 ? ((const float*)p)[i] : b2f(((const bf16*)p)[i]);
}
static __device__ __forceinline__ void ld4(const void* p, size_t i, int isf32, float* o){
    if (isf32) {
        float4 v = *(const float4*)((const float*)p + i);
        o[0]=v.x; o[1]=v.y; o[2]=v.z; o[3]=v.w;
    } else {
        ushort4 u = *(const ushort4*)((const bf16*)p + i);
        o[0]=us2f(u.x); o[1]=us2f(u.y); o[2]=us2f(u.z); o[3]=us2f(u.w);
    }
}

// ---------------------------------------------------------------------------
// dtype detector (1 = harness buffers are f32, 0 = bf16)
// ---------------------------------------------------------------------------
__global__ __launch_bounds__(64) void detect_kernel(const unsigned short* __restrict__ x,
                                                    int* __restrict__ flag)
{
    int big = 0;
    for (int i = threadIdx.x; i < 1024; i += 64) {
        const unsigned short u = x[2*i];
        const int e = (u >> 7) & 0xFF;
        if (e >= 139) big++;
    }
    #pragma unroll
    for (int off = 32; off; off >>= 1) big += __shfl_down(big, off, 64);
    if (threadIdx.x == 0) *flag = (big > 8) ? 1 : 0;
}

// ---------------------------------------------------------------------------
// Elementwise convert harness buffer -> bf16 (8 elems/thread)
// ---------------------------------------------------------------------------
__global__ __launch_bounds__(256) void convert_kernel(const void* __restrict__ in,
                                                      bf16* __restrict__ out, int n,
                                                      const int* __restrict__ flag)
{
    const int f = *flag;
    const int i0 = (blockIdx.x * 256 + threadIdx.x) * 8;
    if (i0 >= n) return;
    float v[8];
    ld4(in, i0, f, v);
    ld4(in, i0 + 4, f, v + 4);
    bf16* o = out + i0;
    #pragma unroll
    for (int k = 0; k < 8; ++k) o[k] = f2b(v[k]);
}

// ---------------------------------------------------------------------------
// Transpose harness weight [R][Cc] -> bf16 out [Cc][R] (row stride R)
// ---------------------------------------------------------------------------
__global__ __launch_bounds__(256) void transpose_kernel(const void* __restrict__ in,
                                                        bf16* __restrict__ out,
                                                        int R, int Cc,
                                                        const int* __restrict__ flag)
{
    const int f = *flag;
    __shared__ float tile[32][33];
    const int c0 = blockIdx.x * 32, r0 = blockIdx.y * 32;
    const int tx = threadIdx.x & 31, ty = threadIdx.x >> 5;  // 32 x 8
    #pragma unroll
    for (int i = 0; i < 4; ++i)
        tile[ty + 8*i][tx] = ldS(in, (size_t)(r0 + ty + 8*i) * Cc + c0 + tx, f);
    __syncthreads();
    #pragma unroll
    for (int i = 0; i < 4; ++i)
        out[(size_t)(c0 + ty + 8*i) * R + r0 + tx] = f2b(tile[tx][ty + 8*i]);
}

// ---------------------------------------------------------------------------
// Transpose V half of kv [4096][4096] (cols 2048..4095 = (h,d)) into
// vT[(b*H+h)*HD + d][t] (row length T_). LDS-tiled, coalesced both sides.
// ---------------------------------------------------------------------------
__global__ __launch_bounds__(256) void transpose_v_kernel(const bf16* __restrict__ kvb,
                                                          bf16* __restrict__ vT)
{
    __shared__ bf16 tile[32][34];
    const int c0 = blockIdx.x * 32;        // v-col 0..2047
    const int r0 = blockIdx.y * 32;        // row 0..4095 (b*T + t)
    const int tx = threadIdx.x & 31, ty = threadIdx.x >> 5;  // 32 x 8
    #pragma unroll
    for (int i = 0; i < 4; ++i)
        tile[ty + 8*i][tx] = kvb[(size_t)(r0 + ty + 8*i) * (H_*256) + H_*128 + c0 + tx];
    __syncthreads();
    const int b  = r0 >> 11;
    const int t0 = r0 & (T_ - 1);
    #pragma unroll
    for (int i = 0; i < 4; ++i) {
        const int c  = c0 + ty + 8*i;
        const int hh = c >> 7, dd = c & 127;
        vT[(((size_t)b*H_ + hh)*HD_ + dd)*T_ + t0 + tx] = tile[tx][ty + 8*i];
    }
}

// ---------------------------------------------------------------------------
// MFMA GEMM: C[M,N] = A[M,K] @ BT[N,K]^T. A,BT bf16; C bf16 or f32 (cf).
// 128x128 tile, BK=32, 4 waves (2x2), 4x4 16x16x32 frags per wave.
// ---------------------------------------------------------------------------
__global__ __launch_bounds__(256) void mfma_gemm(const bf16* __restrict__ A,
                                                 const bf16* __restrict__ BT,
                                                 void* __restrict__ C,
                                                 int N, int K,
                                                 const int* __restrict__ flag, int cH)
{
    const int cf = cH ? *flag : 0;
    __shared__ bf16 As[128 * 32];
    __shared__ bf16 Bs[128 * 32];
    const int tid  = threadIdx.x;
    const int w    = tid >> 6;
    const int lane = tid & 63;
    const int quad = lane >> 4;
    const int l16  = lane & 15;
    const int wm   = w >> 1, wn = w & 1;
    const int bm   = blockIdx.y * 128, bn = blockIdx.x * 128;
    const int lrow = lane >> 2;
    const int lk   = (lane & 3) * 8;

    f32x4 acc[4][4];
    #pragma unroll
    for (int i = 0; i < 4; ++i)
        #pragma unroll
        for (int j = 0; j < 4; ++j)
            acc[i][j] = (f32x4){0.f, 0.f, 0.f, 0.f};

    for (int kk = 0; kk < K; kk += 32) {
        if (kk) __syncthreads();
        #pragma unroll
        for (int c = 0; c < 2; ++c) {
            const int ch  = w * 2 + c;
            const int row = ch * 16 + lrow;
            const bf16* g = A + (size_t)(bm + row) * K + kk + lk;
            __builtin_amdgcn_global_load_lds(
                (const __attribute__((address_space(1))) unsigned int*)g,
                (__attribute__((address_space(3))) unsigned int*)(As + ch * 512),
                16, 0, 0);
        }
        #pragma unroll
        for (int c = 0; c < 2; ++c) {
            const int ch  = w * 2 + c;
            const int row = ch * 16 + lrow;
            const bf16* g = BT + (size_t)(bn + row) * K + kk + lk;
            __builtin_amdgcn_global_load_lds(
                (const __attribute__((address_space(1))) unsigned int*)g,
                (__attribute__((address_space(3))) unsigned int*)(Bs + ch * 512),
                16, 0, 0);
        }
        __syncthreads();

        s16x8 af[4], bfv[4];
        #pragma unroll
        for (int i = 0; i < 4; ++i)
            af[i] = *(const s16x8*)&As[(wm*64 + i*16 + l16) * 32 + quad*8];
        #pragma unroll
        for (int j = 0; j < 4; ++j)
            bfv[j] = *(const s16x8*)&Bs[(wn*64 + j*16 + l16) * 32 + quad*8];
        #pragma unroll
        for (int i = 0; i < 4; ++i)
            #pragma unroll
            for (int j = 0; j < 4; ++j)
                acc[i][j] = __builtin_amdgcn_mfma_f32_16x16x32_bf16(af[i], bfv[j], acc[i][j], 0, 0, 0);
    }

    #pragma unroll
    for (int i = 0; i < 4; ++i) {
        const int crow = bm + wm*64 + i*16 + quad*4;
        #pragma unroll
        for (int r = 0; r < 4; ++r) {
            #pragma unroll
            for (int j = 0; j < 4; ++j) {
                const int ccol = bn + wn*64 + j*16 + l16;
                if (ccol < N) {
                    const size_t idx = (size_t)(crow + r) * N + ccol;
                    if (cf) ((float*)C)[idx] = acc[i][j][r];
                    else    ((bf16*)C)[idx] = f2b(acc[i][j][r]);
                }
            }
        }
    }
}

// ---------------------------------------------------------------------------
// In-place RMSNorm over rows of X [rows, NPER*256] (internal bf16)
// ---------------------------------------------------------------------------
template<int NPER>
__global__ __launch_bounds__(256) void rms_kernel(bf16* __restrict__ X,
                                                  const void* __restrict__ w,
                                                  const int* __restrict__ flag)
{
    const int wf = *flag;
    const int ncols = NPER * 256;
    __shared__ float red[4];
    const int row = blockIdx.x;
    const int tid = threadIdx.x;
    bf16* xr = X + (size_t)row * ncols;
    float vals[NPER];
    float ss = 0.f;
    #pragma unroll
    for (int i = 0; i < NPER; ++i) {
        float v = b2f(xr[tid + i*256]);
        vals[i] = v; ss += v*v;
    }
    #pragma unroll
    for (int off = 32; off; off >>= 1) ss += __shfl_down(ss, off, 64);
    if ((tid & 63) == 0) red[tid >> 6] = ss;
    __syncthreads();
    const float tot = red[0]+red[1]+red[2]+red[3];
    const float rs  = rsqrtf(tot / (float)ncols + 1e-6f);
    #pragma unroll
    for (int i = 0; i < NPER; ++i) {
        const int c = tid + i*256;
        xr[c] = f2b(vals[i] * rs * ldS(w, c, wf));
    }
}

// ---------------------------------------------------------------------------
// k_pe: in-place RMSNorm over 64 cols + RoPE
// ---------------------------------------------------------------------------
__global__ __launch_bounds__(64) void kpe_rms_rope(bf16* __restrict__ X,
                                                   const void* __restrict__ w,
                                                   const int* __restrict__ flag)
{
    const int wf   = *flag;
    const int row  = blockIdx.x;
    const int t    = row & (T_ - 1);
    const int lane = threadIdx.x;
    bf16* xr = X + (size_t)row * RD_;
    const float v = b2f(xr[lane]);
    float ss = v * v;
    #pragma unroll
    for (int off = 32; off; off >>= 1) ss += __shfl_down(ss, off, 64);
    ss = __shfl(ss, 0, 64);
    const float rs = rsqrtf(ss / 64.f + 1e-6f);
    const float xn = v * rs * ldS(w, lane, wf);
    const int   i  = lane & 31;
    const float freq = powf(10000.f, -(float)(2*i) / 64.f);
    const float ang  = (float)t * freq;
    const float s = sinf(ang), c = cosf(ang);
    const float other = __shfl_xor(xn, 32, 64);
    const float o = (lane < 32) ? (xn * c - other * s) : (other * s + xn * c);
    xr[lane] = f2b(o);
}

// ---------------------------------------------------------------------------
// q_pe RoPE in-place: X [B*T, H*64]
// ---------------------------------------------------------------------------
__global__ __launch_bounds__(256) void qpe_rope(bf16* __restrict__ X)
{
    const int row = blockIdx.x;
    const int t   = row & (T_ - 1);
    bf16* xr = X + (size_t)row * (H_ * RD_);
    const int tid = threadIdx.x;
    #pragma unroll
    for (int pp = 0; pp < 2; ++pp) {
        const int p  = tid + pp * 256;
        const int hh = p >> 5;
        const int i  = p & 31;
        const int i0 = hh * 64 + i;
        const int i1 = i0 + 32;
        const float x1 = b2f(xr[i0]), x2 = b2f(xr[i1]);
        const float freq = powf(10000.f, -(float)(2*i) / 64.f);
        const float ang  = (float)t * freq;
        const float s = sinf(ang), c = cosf(ang);
        xr[i0] = f2b(x1 * c - x2 * s);
        xr[i1] = f2b(x1 * s + x2 * c);
    }
}

// ---------------------------------------------------------------------------
// Flash-style MFMA attention v2: register-prefetch pipeline + coalesced V
// staging from pre-transposed vT; raw lgkmcnt-only barriers keep prefetch
// loads in flight across __syncthreads points.
// grid (h, qt-slot, b); qt = 31 - slot (heavy first); XCD = h%8 affinity.
// ---------------------------------------------------------------------------
__global__ __launch_bounds__(256, 2) void flash_attn(const bf16* __restrict__ qnop,
                                                     const bf16* __restrict__ qpe,
                                                     const bf16* __restrict__ kv,
                                                     const bf16* __restrict__ kpe,
                                                     const bf16* __restrict__ vT,
                                                     bf16* __restrict__ y)
{
    __shared__ __align__(16) short Klds[64][208];   // [krow][dim0..191], stride 416B
    __shared__ __align__(16) short Vt[128][72];     // [vdim][krow]
    __shared__ __align__(16) short Plds[4][16][72]; // per-wave P [qrow][krow]

    const int h   = blockIdx.x;
    const int qt  = 31 - (int)blockIdx.y;          // heavy blocks dispatched first
    const int b   = blockIdx.z;
    const int q0  = qt * 64;
    const int tid = threadIdx.x;
    const int w    = tid >> 6;
    const int lane = tid & 63;
    const int quad = lane >> 4;
    const int l16  = lane & 15;
    const int row0 = q0 + w * 16;
    const size_t bT = (size_t)b * T_;
    const int bh  = b * H_ + h;

    // ---- Q fragments (A-layout), loaded once ----
    s16x8 aq[6];
    {
        const size_t r = bT + row0 + l16;
        const bf16* qn = qnop + r * (H_*128) + h*128 + quad*8;
        #pragma unroll
        for (int kk = 0; kk < 4; ++kk) aq[kk] = *(const s16x8*)(qn + kk*32);
        const bf16* qp = qpe + r * (H_*64) + h*64 + quad*8;
        aq[4] = *(const s16x8*)(qp);
        aq[5] = *(const s16x8*)(qp + 32);
    }

    f32x4 o[8];
    #pragma unroll
    for (int i = 0; i < 8; ++i) o[i] = (f32x4){0.f,0.f,0.f,0.f};
    float m_run[4] = {-1e30f,-1e30f,-1e30f,-1e30f};
    float l_run[4] = {0.f,0.f,0.f,0.f};

    // ---- register prefetch buffers ----
    uint4 pK[4], pP[2], pV[4];
    #define PREFETCH(J0) do {                                                          \
        _Pragma("unroll")                                                              \
        for (int c = 0; c < 4; ++c) { const int e = c*256 + tid;                       \
            const int row = e >> 4, ch = e & 15;                                       \
            pK[c] = *(const uint4*)(kv + (bT + (J0) + row) * (H_*256) + h*128 + ch*8); }\
        _Pragma("unroll")                                                              \
        for (int c = 0; c < 2; ++c) { const int e = c*256 + tid;                       \
            const int row = e >> 3, ch = e & 7;                                        \
            pP[c] = *(const uint4*)(kpe + (bT + (J0) + row) * RD_ + ch*8); }           \
        _Pragma("unroll")                                                              \
        for (int c = 0; c < 4; ++c) { const int e = c*256 + tid;                       \
            const int d = e >> 3, ch = e & 7;                                          \
            pV[c] = *(const uint4*)(vT + ((size_t)bh*HD_ + d) * T_ + (J0) + ch*8); }   \
    } while (0)

    PREFETCH(0);

    const int ntiles = qt + 1;
    for (int it = 0; it < ntiles; ++it) {
        const int j0 = it * 64;
        // barrier: prior tile's LDS reads done (lgkm only; vm prefetch stays in flight)
        asm volatile("s_waitcnt lgkmcnt(0)\n\ts_barrier" ::: "memory");

        #pragma unroll
        for (int c = 0; c < 4; ++c) { const int e = c*256 + tid;
            *(uint4*)&Klds[e >> 4][(e & 15)*8] = pK[c]; }
        #pragma unroll
        for (int c = 0; c < 2; ++c) { const int e = c*256 + tid;
            *(uint4*)&Klds[e >> 3][128 + (e & 7)*8] = pP[c]; }
        #pragma unroll
        for (int c = 0; c < 4; ++c) { const int e = c*256 + tid;
            *(uint4*)&Vt[e >> 3][(e & 7)*8] = pV[c]; }

        if (it + 1 < ntiles) PREFETCH(j0 + 64);

        // barrier: LDS writes visible (lgkm only)
        asm volatile("s_waitcnt lgkmcnt(0)\n\ts_barrier" ::: "memory");

        if (j0 <= row0 + 15) {
            const bool needmask = (j0 + 63 > row0);
            f32x4 s[4];
            #pragma unroll
            for (int nsub = 0; nsub < 4; ++nsub) {
                f32x4 acc = (f32x4){0.f,0.f,0.f,0.f};
                #pragma unroll
                for (int kk = 0; kk < 6; ++kk) {
                    const s16x8 bk = *(const s16x8*)&Klds[nsub*16 + l16][kk*32 + quad*8];
                    acc = __builtin_amdgcn_mfma_f32_16x16x32_bf16(aq[kk], bk, acc, 0, 0, 0);
                }
                #pragma unroll
                for (int reg = 0; reg < 4; ++reg) acc[reg] *= SCALE_;
                s[nsub] = acc;
            }
            if (needmask) {
                #pragma unroll
                for (int nsub = 0; nsub < 4; ++nsub)
                    #pragma unroll
                    for (int reg = 0; reg < 4; ++reg) {
                        const int col = j0 + nsub*16 + l16;
                        const int row = row0 + quad*4 + reg;
                        if (col > row) s[nsub][reg] = -1e30f;
                    }
            }
            float mt[4], alpha[4], rs[4];
            #pragma unroll
            for (int reg = 0; reg < 4; ++reg)
                mt[reg] = fmaxf(fmaxf(s[0][reg], s[1][reg]), fmaxf(s[2][reg], s[3][reg]));
            #pragma unroll
            for (int d = 1; d < 16; d <<= 1)
                #pragma unroll
                for (int reg = 0; reg < 4; ++reg)
                    mt[reg] = fmaxf(mt[reg], __shfl_xor(mt[reg], d, 64));
            #pragma unroll
            for (int reg = 0; reg < 4; ++reg) {
                const float mnew = fmaxf(m_run[reg], mt[reg]);
                alpha[reg] = __expf(m_run[reg] - mnew);
                m_run[reg] = mnew;
                rs[reg] = 0.f;
            }
            #pragma unroll
            for (int nsub = 0; nsub < 4; ++nsub)
                #pragma unroll
                for (int reg = 0; reg < 4; ++reg) {
                    const float p = __expf(s[nsub][reg] - m_run[reg]);
                    s[nsub][reg] = p;
                    rs[reg] += p;
                }
            #pragma unroll
            for (int d = 1; d < 16; d <<= 1)
                #pragma unroll
                for (int reg = 0; reg < 4; ++reg)
                    rs[reg] += __shfl_xor(rs[reg], d, 64);
            #pragma unroll
            for (int reg = 0; reg < 4; ++reg)
                l_run[reg] = l_run[reg] * alpha[reg] + rs[reg];

            #pragma unroll
            for (int nsub = 0; nsub < 4; ++nsub)
                #pragma unroll
                for (int reg = 0; reg < 4; ++reg) {
                    const bf16 pv = f2b(s[nsub][reg]);
                    Plds[w][quad*4 + reg][nsub*16 + l16] = *(const short*)&pv;
                }
            #pragma unroll
            for (int n2 = 0; n2 < 8; ++n2)
                #pragma unroll
                for (int reg = 0; reg < 4; ++reg)
                    o[n2][reg] *= alpha[reg];

            const s16x8 ap0 = *(const s16x8*)&Plds[w][l16][quad*8];
            const s16x8 ap1 = *(const s16x8*)&Plds[w][l16][32 + quad*8];
            #pragma unroll
            for (int n2 = 0; n2 < 8; ++n2) {
                const s16x8 bv0 = *(const s16x8*)&Vt[n2*16 + l16][quad*8];
                const s16x8 bv1 = *(const s16x8*)&Vt[n2*16 + l16][32 + quad*8];
                o[n2] = __builtin_amdgcn_mfma_f32_16x16x32_bf16(ap0, bv0, o[n2], 0, 0, 0);
                o[n2] = __builtin_amdgcn_mfma_f32_16x16x32_bf16(ap1, bv1, o[n2], 0, 0, 0);
            }
        }
    }
    #undef PREFETCH

    #pragma unroll
    for (int reg = 0; reg < 4; ++reg) {
        const float inv = 1.f / l_run[reg];
        const size_t r = bT + row0 + quad*4 + reg;
        bf16* yr = y + r * (H_*128) + h*128 + l16;
        #pragma unroll
        for (int n2 = 0; n2 < 8; ++n2)
            yr[n2*16] = f2b(o[n2][reg] * inv);
    }
}

// ---------------------------------------------------------------------------
extern "C" void kernel_launch(void* const* d_in, const int* in_sizes, int n_in,
                              void* d_out, int out_size, void* d_ws, size_t ws_size,
                              hipStream_t stream)
{
    const void* x         = d_in[0];
    const void* Wq_down   = d_in[1];
    const void* q_norm_w  = d_in[2];
    const void* Wq_up     = d_in[3];
    const void* Wq_pe     = d_in[4];
    const void* Wkv_down  = d_in[5];
    const void* kv_norm_w = d_in[6];
    const void* Wkv_up    = d_in[7];
    const void* Wk_pe     = d_in[8];
    const void* kpe_nw    = d_in[9];
    const void* Wo        = d_in[10];

    char* ws = (char*)d_ws;
    int*  flag = (int*)(ws + 0);
    bf16* xb   = (bf16*)(ws + 256);        // [4096,2048] — dead after kpe GEMM
    bf16* cQ   = (bf16*)(ws + 16777472);   // [4096,1536]
    bf16* cKV  = (bf16*)(ws + 29360384);   // [4096, 512]
    bf16* kpeb = (bf16*)(ws + 33554688);   // [4096,  64]
    bf16* qnop = (bf16*)(ws + 34078976);   // [4096,2048]
    bf16* qpeb = (bf16*)(ws + 50856192);   // [4096,1024]
    bf16* kvb  = (bf16*)(ws + 59244800);   // [4096,4096]
    bf16* yb   = (bf16*)(ws + 92799232);   // [4096,2048]
    bf16* Wt   = (bf16*)(ws + 109576448);  // weight-transpose pool (6.29 MB)
    bf16* vT   = xb;                       // reuse xb region: [32][128][2048] 16.8 MB

    const dim3 blk(256);

    detect_kernel<<<1, dim3(64), 0, stream>>>((const unsigned short*)x, flag);
    convert_kernel<<<(B_*T_*C_)/(256*8), blk, 0, stream>>>(x, xb, B_*T_*C_, flag);

    // ---- Q down: x @ Wq_down -> cQ ; rms ----
    transpose_kernel<<<dim3(QLR_/32, C_/32), blk, 0, stream>>>(Wq_down, Wt, C_, QLR_, flag);
    mfma_gemm<<<dim3(QLR_/128, 32), blk, 0, stream>>>(xb, Wt, cQ, QLR_, C_, flag, 0);
    rms_kernel<6><<<B_*T_, blk, 0, stream>>>(cQ, q_norm_w, flag);

    // ---- KV down: x @ Wkv_down -> cKV ; rms ----
    transpose_kernel<<<dim3(KLR_/32, C_/32), blk, 0, stream>>>(Wkv_down, Wt, C_, KLR_, flag);
    mfma_gemm<<<dim3(KLR_/128, 32), blk, 0, stream>>>(xb, Wt, cKV, KLR_, C_, flag, 0);
    rms_kernel<2><<<B_*T_, blk, 0, stream>>>(cKV, kv_norm_w, flag);

    // ---- k_pe: x @ Wk_pe -> kpeb ; rms+rope (BT padded to 128 rows) ----
    transpose_kernel<<<dim3(RD_/32, C_/32), blk, 0, stream>>>(Wk_pe, Wt, C_, RD_, flag);
    mfma_gemm<<<dim3(1, 32), blk, 0, stream>>>(xb, Wt, kpeb, RD_, C_, flag, 0);
    kpe_rms_rope<<<B_*T_, dim3(64), 0, stream>>>(kpeb, kpe_nw, flag);

    // ---- q up-projections ----
    transpose_kernel<<<dim3((H_*HD_)/32, QLR_/32), blk, 0, stream>>>(Wq_up, Wt, QLR_, H_*HD_, flag);
    mfma_gemm<<<dim3((H_*HD_)/128, 32), blk, 0, stream>>>(cQ, Wt, qnop, H_*HD_, QLR_, flag, 0);
    transpose_kernel<<<dim3((H_*RD_)/32, QLR_/32), blk, 0, stream>>>(Wq_pe, Wt, QLR_, H_*RD_, flag);
    mfma_gemm<<<dim3((H_*RD_)/128, 32), blk, 0, stream>>>(cQ, Wt, qpeb, H_*RD_, QLR_, flag, 0);
    qpe_rope<<<B_*T_, blk, 0, stream>>>(qpeb);

    // ---- kv up-projection, then V transpose (xb is dead now) ----
    transpose_kernel<<<dim3((H_*2*HD_)/32, KLR_/32), blk, 0, stream>>>(Wkv_up, Wt, KLR_, H_*2*HD_, flag);
    mfma_gemm<<<dim3((H_*2*HD_)/128, 32), blk, 0, stream>>>(cKV, Wt, kvb, H_*2*HD_, KLR_, flag, 0);
    transpose_v_kernel<<<dim3((H_*HD_)/32, (B_*T_)/32), blk, 0, stream>>>(kvb, vT);

    // ---- attention ----
    flash_attn<<<dim3(H_, T_/64, B_), blk, 0, stream>>>(qnop, qpeb, kvb, kpeb, vT, yb);

    // ---- output projection (dtype of d_out per flag) ----
    transpose_kernel<<<dim3(C_/32, (H_*HD_)/32), blk, 0, stream>>>(Wo, Wt, H_*HD_, C_, flag);
    mfma_gemm<<<dim3(C_/128, 32), blk, 0, stream>>>(yb, Wt, d_out, C_, H_*HD_, flag, 1);
}

// Round 6
// 616.628 us; speedup vs baseline: 1.1910x; 1.1910x over previous
//
#include <hip/hip_runtime.h>
#include <hip/hip_bf16.h>
#include <cmath>

typedef __hip_bfloat16 bf16;
typedef __attribute__((ext_vector_type(8))) short s16x8;
typedef __attribute__((ext_vector_type(4))) float f32x4;

#define B_   2
#define T_   2048
#define C_   2048
#define H_   16
#define HD_  128
#define RD_  64
#define QLR_ 1536
#define KLR_ 512
#define SCALE_ 0.07216878364870322f   // (128+64)^-0.5

static __device__ __forceinline__ float b2f(bf16 v){ return __bfloat162float(v); }
static __device__ __forceinline__ bf16  f2b(float v){ return __float2bfloat16(v); }
static __device__ __forceinline__ float us2f(unsigned short u){
    union { unsigned short s[2]; float f; } v; v.s[0]=0; v.s[1]=u; return v.f;
}
static __device__ __forceinline__ float ldS(const void* p, size_t i, int isf32){
    return isf32 ? ((const float*)p)[i] : b2f(((const bf16*)p)[i]);
}
static __device__ __forceinline__ void ld4(const void* p, size_t i, int isf32, float* o){
    if (isf32) {
        float4 v = *(const float4*)((const float*)p + i);
        o[0]=v.x; o[1]=v.y; o[2]=v.z; o[3]=v.w;
    } else {
        ushort4 u = *(const ushort4*)((const bf16*)p + i);
        o[0]=us2f(u.x); o[1]=us2f(u.y); o[2]=us2f(u.z); o[3]=us2f(u.w);
    }
}

// ---------------------------------------------------------------------------
// dtype detector (1 = harness buffers are f32, 0 = bf16)
// ---------------------------------------------------------------------------
__global__ __launch_bounds__(64) void detect_kernel(const unsigned short* __restrict__ x,
                                                    int* __restrict__ flag)
{
    int big = 0;
    for (int i = threadIdx.x; i < 1024; i += 64) {
        const unsigned short u = x[2*i];
        const int e = (u >> 7) & 0xFF;
        if (e >= 139) big++;
    }
    #pragma unroll
    for (int off = 32; off; off >>= 1) big += __shfl_down(big, off, 64);
    if (threadIdx.x == 0) *flag = (big > 8) ? 1 : 0;
}

// ---------------------------------------------------------------------------
// Elementwise convert harness buffer -> bf16 (8 elems/thread)
// ---------------------------------------------------------------------------
__global__ __launch_bounds__(256) void convert_kernel(const void* __restrict__ in,
                                                      bf16* __restrict__ out, int n,
                                                      const int* __restrict__ flag)
{
    const int f = *flag;
    const int i0 = (blockIdx.x * 256 + threadIdx.x) * 8;
    if (i0 >= n) return;
    float v[8];
    ld4(in, i0, f, v);
    ld4(in, i0 + 4, f, v + 4);
    bf16* o = out + i0;
    #pragma unroll
    for (int k = 0; k < 8; ++k) o[k] = f2b(v[k]);
}

// ---------------------------------------------------------------------------
// Transpose harness weight [R][Cc] -> bf16 out [Cc][R] (row stride R)
// ---------------------------------------------------------------------------
__global__ __launch_bounds__(256) void transpose_kernel(const void* __restrict__ in,
                                                        bf16* __restrict__ out,
                                                        int R, int Cc,
                                                        const int* __restrict__ flag)
{
    const int f = *flag;
    __shared__ float tile[32][33];
    const int c0 = blockIdx.x * 32, r0 = blockIdx.y * 32;
    const int tx = threadIdx.x & 31, ty = threadIdx.x >> 5;  // 32 x 8
    #pragma unroll
    for (int i = 0; i < 4; ++i)
        tile[ty + 8*i][tx] = ldS(in, (size_t)(r0 + ty + 8*i) * Cc + c0 + tx, f);
    __syncthreads();
    #pragma unroll
    for (int i = 0; i < 4; ++i)
        out[(size_t)(c0 + ty + 8*i) * R + r0 + tx] = f2b(tile[tx][ty + 8*i]);
}

// ---------------------------------------------------------------------------
// Transpose V half of kv [4096][4096] (cols 2048..4095 = (h,d)) into
// vT[(b*H+h)*HD + d][t] (row length T_). LDS-tiled, coalesced both sides.
// ---------------------------------------------------------------------------
__global__ __launch_bounds__(256) void transpose_v_kernel(const bf16* __restrict__ kvb,
                                                          bf16* __restrict__ vT)
{
    __shared__ bf16 tile[32][34];
    const int c0 = blockIdx.x * 32;        // v-col 0..2047
    const int r0 = blockIdx.y * 32;        // row 0..4095 (b*T + t)
    const int tx = threadIdx.x & 31, ty = threadIdx.x >> 5;  // 32 x 8
    #pragma unroll
    for (int i = 0; i < 4; ++i)
        tile[ty + 8*i][tx] = kvb[(size_t)(r0 + ty + 8*i) * (H_*256) + H_*128 + c0 + tx];
    __syncthreads();
    const int b  = r0 >> 11;
    const int t0 = r0 & (T_ - 1);
    #pragma unroll
    for (int i = 0; i < 4; ++i) {
        const int c  = c0 + ty + 8*i;
        const int hh = c >> 7, dd = c & 127;
        vT[(((size_t)b*H_ + hh)*HD_ + dd)*T_ + t0 + tx] = tile[tx][ty + 8*i];
    }
}

// ---------------------------------------------------------------------------
// MFMA GEMM: C[M,N] = A[M,K] @ BT[N,K]^T. A,BT bf16; C bf16 or f32 (cf).
// 128x128 tile, BK=32, 4 waves (2x2), 4x4 16x16x32 frags per wave.
// ---------------------------------------------------------------------------
__global__ __launch_bounds__(256) void mfma_gemm(const bf16* __restrict__ A,
                                                 const bf16* __restrict__ BT,
                                                 void* __restrict__ C,
                                                 int N, int K,
                                                 const int* __restrict__ flag, int cH)
{
    const int cf = cH ? *flag : 0;
    __shared__ bf16 As[128 * 32];
    __shared__ bf16 Bs[128 * 32];
    const int tid  = threadIdx.x;
    const int w    = tid >> 6;
    const int lane = tid & 63;
    const int quad = lane >> 4;
    const int l16  = lane & 15;
    const int wm   = w >> 1, wn = w & 1;
    const int bm   = blockIdx.y * 128, bn = blockIdx.x * 128;
    const int lrow = lane >> 2;
    const int lk   = (lane & 3) * 8;

    f32x4 acc[4][4];
    #pragma unroll
    for (int i = 0; i < 4; ++i)
        #pragma unroll
        for (int j = 0; j < 4; ++j)
            acc[i][j] = (f32x4){0.f, 0.f, 0.f, 0.f};

    for (int kk = 0; kk < K; kk += 32) {
        if (kk) __syncthreads();
        #pragma unroll
        for (int c = 0; c < 2; ++c) {
            const int ch  = w * 2 + c;
            const int row = ch * 16 + lrow;
            const bf16* g = A + (size_t)(bm + row) * K + kk + lk;
            __builtin_amdgcn_global_load_lds(
                (const __attribute__((address_space(1))) unsigned int*)g,
                (__attribute__((address_space(3))) unsigned int*)(As + ch * 512),
                16, 0, 0);
        }
        #pragma unroll
        for (int c = 0; c < 2; ++c) {
            const int ch  = w * 2 + c;
            const int row = ch * 16 + lrow;
            const bf16* g = BT + (size_t)(bn + row) * K + kk + lk;
            __builtin_amdgcn_global_load_lds(
                (const __attribute__((address_space(1))) unsigned int*)g,
                (__attribute__((address_space(3))) unsigned int*)(Bs + ch * 512),
                16, 0, 0);
        }
        __syncthreads();

        s16x8 af[4], bfv[4];
        #pragma unroll
        for (int i = 0; i < 4; ++i)
            af[i] = *(const s16x8*)&As[(wm*64 + i*16 + l16) * 32 + quad*8];
        #pragma unroll
        for (int j = 0; j < 4; ++j)
            bfv[j] = *(const s16x8*)&Bs[(wn*64 + j*16 + l16) * 32 + quad*8];
        #pragma unroll
        for (int i = 0; i < 4; ++i)
            #pragma unroll
            for (int j = 0; j < 4; ++j)
                acc[i][j] = __builtin_amdgcn_mfma_f32_16x16x32_bf16(af[i], bfv[j], acc[i][j], 0, 0, 0);
    }

    #pragma unroll
    for (int i = 0; i < 4; ++i) {
        const int crow = bm + wm*64 + i*16 + quad*4;
        #pragma unroll
        for (int r = 0; r < 4; ++r) {
            #pragma unroll
            for (int j = 0; j < 4; ++j) {
                const int ccol = bn + wn*64 + j*16 + l16;
                if (ccol < N) {
                    const size_t idx = (size_t)(crow + r) * N + ccol;
                    if (cf) ((float*)C)[idx] = acc[i][j][r];
                    else    ((bf16*)C)[idx] = f2b(acc[i][j][r]);
                }
            }
        }
    }
}

// ---------------------------------------------------------------------------
// In-place RMSNorm over rows of X [rows, NPER*256] (internal bf16)
// ---------------------------------------------------------------------------
template<int NPER>
__global__ __launch_bounds__(256) void rms_kernel(bf16* __restrict__ X,
                                                  const void* __restrict__ w,
                                                  const int* __restrict__ flag)
{
    const int wf = *flag;
    const int ncols = NPER * 256;
    __shared__ float red[4];
    const int row = blockIdx.x;
    const int tid = threadIdx.x;
    bf16* xr = X + (size_t)row * ncols;
    float vals[NPER];
    float ss = 0.f;
    #pragma unroll
    for (int i = 0; i < NPER; ++i) {
        float v = b2f(xr[tid + i*256]);
        vals[i] = v; ss += v*v;
    }
    #pragma unroll
    for (int off = 32; off; off >>= 1) ss += __shfl_down(ss, off, 64);
    if ((tid & 63) == 0) red[tid >> 6] = ss;
    __syncthreads();
    const float tot = red[0]+red[1]+red[2]+red[3];
    const float rs  = rsqrtf(tot / (float)ncols + 1e-6f);
    #pragma unroll
    for (int i = 0; i < NPER; ++i) {
        const int c = tid + i*256;
        xr[c] = f2b(vals[i] * rs * ldS(w, c, wf));
    }
}

// ---------------------------------------------------------------------------
// k_pe: in-place RMSNorm over 64 cols + RoPE
// ---------------------------------------------------------------------------
__global__ __launch_bounds__(64) void kpe_rms_rope(bf16* __restrict__ X,
                                                   const void* __restrict__ w,
                                                   const int* __restrict__ flag)
{
    const int wf   = *flag;
    const int row  = blockIdx.x;
    const int t    = row & (T_ - 1);
    const int lane = threadIdx.x;
    bf16* xr = X + (size_t)row * RD_;
    const float v = b2f(xr[lane]);
    float ss = v * v;
    #pragma unroll
    for (int off = 32; off; off >>= 1) ss += __shfl_down(ss, off, 64);
    ss = __shfl(ss, 0, 64);
    const float rs = rsqrtf(ss / 64.f + 1e-6f);
    const float xn = v * rs * ldS(w, lane, wf);
    const int   i  = lane & 31;
    const float freq = powf(10000.f, -(float)(2*i) / 64.f);
    const float ang  = (float)t * freq;
    const float s = sinf(ang), c = cosf(ang);
    const float other = __shfl_xor(xn, 32, 64);
    const float o = (lane < 32) ? (xn * c - other * s) : (other * s + xn * c);
    xr[lane] = f2b(o);
}

// ---------------------------------------------------------------------------
// q_pe RoPE in-place: X [B*T, H*64]
// ---------------------------------------------------------------------------
__global__ __launch_bounds__(256) void qpe_rope(bf16* __restrict__ X)
{
    const int row = blockIdx.x;
    const int t   = row & (T_ - 1);
    bf16* xr = X + (size_t)row * (H_ * RD_);
    const int tid = threadIdx.x;
    #pragma unroll
    for (int pp = 0; pp < 2; ++pp) {
        const int p  = tid + pp * 256;
        const int hh = p >> 5;
        const int i  = p & 31;
        const int i0 = hh * 64 + i;
        const int i1 = i0 + 32;
        const float x1 = b2f(xr[i0]), x2 = b2f(xr[i1]);
        const float freq = powf(10000.f, -(float)(2*i) / 64.f);
        const float ang  = (float)t * freq;
        const float s = sinf(ang), c = cosf(ang);
        xr[i0] = f2b(x1 * c - x2 * s);
        xr[i1] = f2b(x1 * s + x2 * c);
    }
}

// ---------------------------------------------------------------------------
// Flash-style MFMA attention v3: register-prefetch pipeline with NAMED
// scalar uint4 prefetch vars (R5's arrays were demoted to scratch ->
// 574 MB/dispatch spill traffic; named scalars force register allocation).
// lgkmcnt-only raw barriers keep global prefetch loads in flight.
// ---------------------------------------------------------------------------
__global__ __launch_bounds__(256, 2) void flash_attn(const bf16* __restrict__ qnop,
                                                     const bf16* __restrict__ qpe,
                                                     const bf16* __restrict__ kv,
                                                     const bf16* __restrict__ kpe,
                                                     const bf16* __restrict__ vT,
                                                     bf16* __restrict__ y)
{
    __shared__ __align__(16) short Klds[64][200];   // [krow][dim0..191]
    __shared__ __align__(16) short Vt[128][72];     // [vdim][krow]
    __shared__ __align__(16) short Plds[4][16][72]; // per-wave P [qrow][krow]

    const int h   = blockIdx.x;
    const int qt  = 31 - (int)blockIdx.y;          // heavy blocks dispatched first
    const int b   = blockIdx.z;
    const int q0  = qt * 64;
    const int tid = threadIdx.x;
    const int w    = tid >> 6;
    const int lane = tid & 63;
    const int quad = lane >> 4;
    const int l16  = lane & 15;
    const int row0 = q0 + w * 16;
    const size_t bT = (size_t)b * T_;
    const int bh  = b * H_ + h;

    // per-thread staging coordinates (constant across tiles)
    const int kR = tid >> 4, kC = (tid & 15) * 8;   // K rows kR+{0,16,32,48}
    const int pR = tid >> 3, pC = (tid & 7) * 8;    // kpe rows pR+{0,32}
    const int vD = tid >> 3, vC = (tid & 7) * 8;    // v dims vD+{0,32,64,96}

    const bf16* gK = kv  + (bT + kR) * (H_*256) + h*128 + kC;
    const bf16* gP = kpe + (bT + pR) * RD_ + pC;
    const bf16* gV = vT  + ((size_t)bh*HD_ + vD) * T_ + vC;

    // ---- Q fragments (A-layout), loaded once ----
    s16x8 aq[6];
    {
        const size_t r = bT + row0 + l16;
        const bf16* qn = qnop + r * (H_*128) + h*128 + quad*8;
        #pragma unroll
        for (int kk = 0; kk < 4; ++kk) aq[kk] = *(const s16x8*)(qn + kk*32);
        const bf16* qp = qpe + r * (H_*64) + h*64 + quad*8;
        aq[4] = *(const s16x8*)(qp);
        aq[5] = *(const s16x8*)(qp + 32);
    }

    f32x4 o[8];
    #pragma unroll
    for (int i = 0; i < 8; ++i) o[i] = (f32x4){0.f,0.f,0.f,0.f};
    float m_run[4] = {-1e30f,-1e30f,-1e30f,-1e30f};
    float l_run[4] = {0.f,0.f,0.f,0.f};

    // ---- named prefetch registers (NOT arrays — must stay in VGPRs) ----
    uint4 k0, k1, k2, k3, p0, p1, v0, v1, v2, v3;
    #define PF(J0) do {                                                     \
        const bf16* a_ = gK + (size_t)(J0) * (H_*256);                      \
        k0 = *(const uint4*)(a_);                                           \
        k1 = *(const uint4*)(a_ + 16*(H_*256));                             \
        k2 = *(const uint4*)(a_ + 32*(H_*256));                             \
        k3 = *(const uint4*)(a_ + 48*(H_*256));                             \
        const bf16* p_ = gP + (size_t)(J0) * RD_;                           \
        p0 = *(const uint4*)(p_);                                           \
        p1 = *(const uint4*)(p_ + 32*RD_);                                  \
        const bf16* v_ = gV + (J0);                                         \
        v0 = *(const uint4*)(v_);                                           \
        v1 = *(const uint4*)(v_ + 32*T_);                                   \
        v2 = *(const uint4*)(v_ + 64*T_);                                   \
        v3 = *(const uint4*)(v_ + 96*T_);                                   \
    } while (0)

    PF(0);

    const int ntiles = qt + 1;
    for (int it = 0; it < ntiles; ++it) {
        const int j0 = it * 64;
        // prior tile's LDS reads done (lgkm only; vm prefetch stays in flight)
        asm volatile("s_waitcnt lgkmcnt(0)\n\ts_barrier" ::: "memory");

        *(uint4*)&Klds[kR     ][kC]      = k0;
        *(uint4*)&Klds[kR + 16][kC]      = k1;
        *(uint4*)&Klds[kR + 32][kC]      = k2;
        *(uint4*)&Klds[kR + 48][kC]      = k3;
        *(uint4*)&Klds[pR     ][128+pC]  = p0;
        *(uint4*)&Klds[pR + 32][128+pC]  = p1;
        *(uint4*)&Vt[vD     ][vC]        = v0;
        *(uint4*)&Vt[vD + 32][vC]        = v1;
        *(uint4*)&Vt[vD + 64][vC]        = v2;
        *(uint4*)&Vt[vD + 96][vC]        = v3;

        if (it + 1 < ntiles) PF(j0 + 64);

        // LDS writes visible (lgkm only)
        asm volatile("s_waitcnt lgkmcnt(0)\n\ts_barrier" ::: "memory");

        if (j0 <= row0 + 15) {
            const bool needmask = (j0 + 63 > row0);
            f32x4 s[4];
            #pragma unroll
            for (int nsub = 0; nsub < 4; ++nsub) {
                f32x4 acc = (f32x4){0.f,0.f,0.f,0.f};
                #pragma unroll
                for (int kk = 0; kk < 6; ++kk) {
                    const s16x8 bk = *(const s16x8*)&Klds[nsub*16 + l16][kk*32 + quad*8];
                    acc = __builtin_amdgcn_mfma_f32_16x16x32_bf16(aq[kk], bk, acc, 0, 0, 0);
                }
                #pragma unroll
                for (int reg = 0; reg < 4; ++reg) acc[reg] *= SCALE_;
                s[nsub] = acc;
            }
            if (needmask) {
                #pragma unroll
                for (int nsub = 0; nsub < 4; ++nsub)
                    #pragma unroll
                    for (int reg = 0; reg < 4; ++reg) {
                        const int col = j0 + nsub*16 + l16;
                        const int row = row0 + quad*4 + reg;
                        if (col > row) s[nsub][reg] = -1e30f;
                    }
            }
            float mt[4], alpha[4], rs[4];
            #pragma unroll
            for (int reg = 0; reg < 4; ++reg)
                mt[reg] = fmaxf(fmaxf(s[0][reg], s[1][reg]), fmaxf(s[2][reg], s[3][reg]));
            #pragma unroll
            for (int d = 1; d < 16; d <<= 1)
                #pragma unroll
                for (int reg = 0; reg < 4; ++reg)
                    mt[reg] = fmaxf(mt[reg], __shfl_xor(mt[reg], d, 64));
            #pragma unroll
            for (int reg = 0; reg < 4; ++reg) {
                const float mnew = fmaxf(m_run[reg], mt[reg]);
                alpha[reg] = __expf(m_run[reg] - mnew);
                m_run[reg] = mnew;
                rs[reg] = 0.f;
            }
            #pragma unroll
            for (int nsub = 0; nsub < 4; ++nsub)
                #pragma unroll
                for (int reg = 0; reg < 4; ++reg) {
                    const float p = __expf(s[nsub][reg] - m_run[reg]);
                    s[nsub][reg] = p;
                    rs[reg] += p;
                }
            #pragma unroll
            for (int d = 1; d < 16; d <<= 1)
                #pragma unroll
                for (int reg = 0; reg < 4; ++reg)
                    rs[reg] += __shfl_xor(rs[reg], d, 64);
            #pragma unroll
            for (int reg = 0; reg < 4; ++reg)
                l_run[reg] = l_run[reg] * alpha[reg] + rs[reg];

            #pragma unroll
            for (int nsub = 0; nsub < 4; ++nsub)
                #pragma unroll
                for (int reg = 0; reg < 4; ++reg) {
                    const bf16 pv = f2b(s[nsub][reg]);
                    Plds[w][quad*4 + reg][nsub*16 + l16] = *(const short*)&pv;
                }
            #pragma unroll
            for (int n2 = 0; n2 < 8; ++n2)
                #pragma unroll
                for (int reg = 0; reg < 4; ++reg)
                    o[n2][reg] *= alpha[reg];

            const s16x8 ap0 = *(const s16x8*)&Plds[w][l16][quad*8];
            const s16x8 ap1 = *(const s16x8*)&Plds[w][l16][32 + quad*8];
            #pragma unroll
            for (int n2 = 0; n2 < 8; ++n2) {
                const s16x8 bv0 = *(const s16x8*)&Vt[n2*16 + l16][quad*8];
                const s16x8 bv1 = *(const s16x8*)&Vt[n2*16 + l16][32 + quad*8];
                o[n2] = __builtin_amdgcn_mfma_f32_16x16x32_bf16(ap0, bv0, o[n2], 0, 0, 0);
                o[n2] = __builtin_amdgcn_mfma_f32_16x16x32_bf16(ap1, bv1, o[n2], 0, 0, 0);
            }
        }
    }
    #undef PF

    #pragma unroll
    for (int reg = 0; reg < 4; ++reg) {
        const float inv = 1.f / l_run[reg];
        const size_t r = bT + row0 + quad*4 + reg;
        bf16* yr = y + r * (H_*128) + h*128 + l16;
        #pragma unroll
        for (int n2 = 0; n2 < 8; ++n2)
            yr[n2*16] = f2b(o[n2][reg] * inv);
    }
}

// ---------------------------------------------------------------------------
extern "C" void kernel_launch(void* const* d_in, const int* in_sizes, int n_in,
                              void* d_out, int out_size, void* d_ws, size_t ws_size,
                              hipStream_t stream)
{
    const void* x         = d_in[0];
    const void* Wq_down   = d_in[1];
    const void* q_norm_w  = d_in[2];
    const void* Wq_up     = d_in[3];
    const void* Wq_pe     = d_in[4];
    const void* Wkv_down  = d_in[5];
    const void* kv_norm_w = d_in[6];
    const void* Wkv_up    = d_in[7];
    const void* Wk_pe     = d_in[8];
    const void* kpe_nw    = d_in[9];
    const void* Wo        = d_in[10];

    char* ws = (char*)d_ws;
    int*  flag = (int*)(ws + 0);
    bf16* xb   = (bf16*)(ws + 256);        // [4096,2048] — dead after kpe GEMM
    bf16* cQ   = (bf16*)(ws + 16777472);   // [4096,1536]
    bf16* cKV  = (bf16*)(ws + 29360384);   // [4096, 512]
    bf16* kpeb = (bf16*)(ws + 33554688);   // [4096,  64]
    bf16* qnop = (bf16*)(ws + 34078976);   // [4096,2048]
    bf16* qpeb = (bf16*)(ws + 50856192);   // [4096,1024]
    bf16* kvb  = (bf16*)(ws + 59244800);   // [4096,4096]
    bf16* yb   = (bf16*)(ws + 92799232);   // [4096,2048]
    bf16* Wt   = (bf16*)(ws + 109576448);  // weight-transpose pool (6.29 MB)
    bf16* vT   = xb;                       // reuse xb region: [32][128][2048]

    const dim3 blk(256);

    detect_kernel<<<1, dim3(64), 0, stream>>>((const unsigned short*)x, flag);
    convert_kernel<<<(B_*T_*C_)/(256*8), blk, 0, stream>>>(x, xb, B_*T_*C_, flag);

    // ---- Q down: x @ Wq_down -> cQ ; rms ----
    transpose_kernel<<<dim3(QLR_/32, C_/32), blk, 0, stream>>>(Wq_down, Wt, C_, QLR_, flag);
    mfma_gemm<<<dim3(QLR_/128, 32), blk, 0, stream>>>(xb, Wt, cQ, QLR_, C_, flag, 0);
    rms_kernel<6><<<B_*T_, blk, 0, stream>>>(cQ, q_norm_w, flag);

    // ---- KV down: x @ Wkv_down -> cKV ; rms ----
    transpose_kernel<<<dim3(KLR_/32, C_/32), blk, 0, stream>>>(Wkv_down, Wt, C_, KLR_, flag);
    mfma_gemm<<<dim3(KLR_/128, 32), blk, 0, stream>>>(xb, Wt, cKV, KLR_, C_, flag, 0);
    rms_kernel<2><<<B_*T_, blk, 0, stream>>>(cKV, kv_norm_w, flag);

    // ---- k_pe: x @ Wk_pe -> kpeb ; rms+rope (BT padded to 128 rows) ----
    transpose_kernel<<<dim3(RD_/32, C_/32), blk, 0, stream>>>(Wk_pe, Wt, C_, RD_, flag);
    mfma_gemm<<<dim3(1, 32), blk, 0, stream>>>(xb, Wt, kpeb, RD_, C_, flag, 0);
    kpe_rms_rope<<<B_*T_, dim3(64), 0, stream>>>(kpeb, kpe_nw, flag);

    // ---- q up-projections ----
    transpose_kernel<<<dim3((H_*HD_)/32, QLR_/32), blk, 0, stream>>>(Wq_up, Wt, QLR_, H_*HD_, flag);
    mfma_gemm<<<dim3((H_*HD_)/128, 32), blk, 0, stream>>>(cQ, Wt, qnop, H_*HD_, QLR_, flag, 0);
    transpose_kernel<<<dim3((H_*RD_)/32, QLR_/32), blk, 0, stream>>>(Wq_pe, Wt, QLR_, H_*RD_, flag);
    mfma_gemm<<<dim3((H_*RD_)/128, 32), blk, 0, stream>>>(cQ, Wt, qpeb, H_*RD_, QLR_, flag, 0);
    qpe_rope<<<B_*T_, blk, 0, stream>>>(qpeb);

    // ---- kv up-projection, then V transpose (xb is dead now) ----
    transpose_kernel<<<dim3((H_*2*HD_)/32, KLR_/32), blk, 0, stream>>>(Wkv_up, Wt, KLR_, H_*2*HD_, flag);
    mfma_gemm<<<dim3((H_*2*HD_)/128, 32), blk, 0, stream>>>(cKV, Wt, kvb, H_*2*HD_, KLR_, flag, 0);
    transpose_v_kernel<<<dim3((H_*HD_)/32, (B_*T_)/32), blk, 0, stream>>>(kvb, vT);

    // ---- attention ----
    flash_attn<<<dim3(H_, T_/64, B_), blk, 0, stream>>>(qnop, qpeb, kvb, kpeb, vT, yb);

    // ---- output projection (dtype of d_out per flag) ----
    transpose_kernel<<<dim3(C_/32, (H_*HD_)/32), blk, 0, stream>>>(Wo, Wt, H_*HD_, C_, flag);
    mfma_gemm<<<dim3(C_/128, 32), blk, 0, stream>>>(yb, Wt, d_out, C_, H_*HD_, flag, 1);
}

// Round 7
// 511.046 us; speedup vs baseline: 1.4371x; 1.2066x over previous
//
#include <hip/hip_runtime.h>
#include <hip/hip_bf16.h>
#include <cmath>

typedef __hip_bfloat16 bf16;
typedef __attribute__((ext_vector_type(8))) short s16x8;
typedef __attribute__((ext_vector_type(4))) float f32x4;

#define B_   2
#define T_   2048
#define C_   2048
#define H_   16
#define HD_  128
#define RD_  64
#define QLR_ 1536
#define KLR_ 512
#define SCALE_ 0.07216878364870322f   // (128+64)^-0.5

static __device__ __forceinline__ float b2f(bf16 v){ return __bfloat162float(v); }
static __device__ __forceinline__ bf16  f2b(float v){ return __float2bfloat16(v); }
static __device__ __forceinline__ float us2f(unsigned short u){
    union { unsigned short s[2]; float f; } v; v.s[0]=0; v.s[1]=u; return v.f;
}
static __device__ __forceinline__ float ldS(const void* p, size_t i, int isf32){
    return isf32 ? ((const float*)p)[i] : b2f(((const bf16*)p)[i]);
}
static __device__ __forceinline__ void ld4(const void* p, size_t i, int isf32, float* o){
    if (isf32) {
        float4 v = *(const float4*)((const float*)p + i);
        o[0]=v.x; o[1]=v.y; o[2]=v.z; o[3]=v.w;
    } else {
        ushort4 u = *(const ushort4*)((const bf16*)p + i);
        o[0]=us2f(u.x); o[1]=us2f(u.y); o[2]=us2f(u.z); o[3]=us2f(u.w);
    }
}

// ---------------------------------------------------------------------------
// dtype detector (1 = harness buffers are f32, 0 = bf16)
// ---------------------------------------------------------------------------
__global__ __launch_bounds__(64) void detect_kernel(const unsigned short* __restrict__ x,
                                                    int* __restrict__ flag)
{
    int big = 0;
    for (int i = threadIdx.x; i < 1024; i += 64) {
        const unsigned short u = x[2*i];
        const int e = (u >> 7) & 0xFF;
        if (e >= 139) big++;
    }
    #pragma unroll
    for (int off = 32; off; off >>= 1) big += __shfl_down(big, off, 64);
    if (threadIdx.x == 0) *flag = (big > 8) ? 1 : 0;
}

// ---------------------------------------------------------------------------
// Elementwise convert harness buffer -> bf16 (8 elems/thread)
// ---------------------------------------------------------------------------
__global__ __launch_bounds__(256) void convert_kernel(const void* __restrict__ in,
                                                      bf16* __restrict__ out, int n,
                                                      const int* __restrict__ flag)
{
    const int f = *flag;
    const int i0 = (blockIdx.x * 256 + threadIdx.x) * 8;
    if (i0 >= n) return;
    float v[8];
    ld4(in, i0, f, v);
    ld4(in, i0 + 4, f, v + 4);
    bf16* o = out + i0;
    #pragma unroll
    for (int k = 0; k < 8; ++k) o[k] = f2b(v[k]);
}

// ---------------------------------------------------------------------------
// Batched transpose: several harness weights [R][Cc] -> bf16 [Cc][R].
// Descriptor table passed by value; flattened grid, linear segment search.
// ---------------------------------------------------------------------------
struct TDesc { const void* in; bf16* out; int R, Cc, blkStart, nx; };
struct TBatch { TDesc d[5]; int nseg; };

__global__ __launch_bounds__(256) void transpose_batch(TBatch tb,
                                                       const int* __restrict__ flag)
{
    const int f = *flag;
    const int bid = blockIdx.x;
    int s = 0;
    #pragma unroll
    for (int i = 1; i < 5; ++i)
        if (i < tb.nseg && bid >= tb.d[i].blkStart) s = i;
    const TDesc d = tb.d[s];
    const int local = bid - d.blkStart;
    const int c0 = (local % d.nx) * 32;
    const int r0 = (local / d.nx) * 32;

    __shared__ float tile[32][33];
    const int tx = threadIdx.x & 31, ty = threadIdx.x >> 5;  // 32 x 8
    #pragma unroll
    for (int i = 0; i < 4; ++i)
        tile[ty + 8*i][tx] = ldS(d.in, (size_t)(r0 + ty + 8*i) * d.Cc + c0 + tx, f);
    __syncthreads();
    #pragma unroll
    for (int i = 0; i < 4; ++i)
        d.out[(size_t)(c0 + ty + 8*i) * d.R + r0 + tx] = f2b(tile[tx][ty + 8*i]);
}

// ---------------------------------------------------------------------------
// Transpose V half of kv [4096][4096] into vT[(b*H+h)*HD + d][t].
// ---------------------------------------------------------------------------
__global__ __launch_bounds__(256) void transpose_v_kernel(const bf16* __restrict__ kvb,
                                                          bf16* __restrict__ vT)
{
    __shared__ bf16 tile[32][34];
    const int c0 = blockIdx.x * 32;        // v-col 0..2047
    const int r0 = blockIdx.y * 32;        // row 0..4095 (b*T + t)
    const int tx = threadIdx.x & 31, ty = threadIdx.x >> 5;
    #pragma unroll
    for (int i = 0; i < 4; ++i)
        tile[ty + 8*i][tx] = kvb[(size_t)(r0 + ty + 8*i) * (H_*256) + H_*128 + c0 + tx];
    __syncthreads();
    const int b  = r0 >> 11;
    const int t0 = r0 & (T_ - 1);
    #pragma unroll
    for (int i = 0; i < 4; ++i) {
        const int c  = c0 + ty + 8*i;
        const int hh = c >> 7, dd = c & 127;
        vT[(((size_t)b*H_ + hh)*HD_ + dd)*T_ + t0 + tx] = tile[tx][ty + 8*i];
    }
}

// ---------------------------------------------------------------------------
// MFMA GEMM with segmented output: C[M,N] = A[M,K] @ BT[N,K]^T.
// Segment boundaries are multiples of 128 so each block writes one segment.
// 128x128 tile, BK=32, 4 waves (2x2), 4x4 16x16x32 frags per wave.
// ---------------------------------------------------------------------------
struct GOuts { void* p[3]; int start[3]; int stride[3]; int nseg; };

__global__ __launch_bounds__(256) void mfma_gemm(const bf16* __restrict__ A,
                                                 const bf16* __restrict__ BT,
                                                 GOuts go, int N, int K,
                                                 const int* __restrict__ flag, int cH)
{
    const int cf = cH ? *flag : 0;
    __shared__ bf16 As[128 * 32];
    __shared__ bf16 Bs[128 * 32];
    const int tid  = threadIdx.x;
    const int w    = tid >> 6;
    const int lane = tid & 63;
    const int quad = lane >> 4;
    const int l16  = lane & 15;
    const int wm   = w >> 1, wn = w & 1;
    const int bm   = blockIdx.y * 128, bn = blockIdx.x * 128;
    const int lrow = lane >> 2;
    const int lk   = (lane & 3) * 8;

    // output segment for this block (bn aligned to segment boundaries)
    int seg = 0;
    #pragma unroll
    for (int i = 1; i < 3; ++i)
        if (i < go.nseg && bn >= go.start[i]) seg = i;
    void* const dstp   = go.p[seg];
    const int  dstoff  = go.start[seg];
    const int  dstride = go.stride[seg];

    f32x4 acc[4][4];
    #pragma unroll
    for (int i = 0; i < 4; ++i)
        #pragma unroll
        for (int j = 0; j < 4; ++j)
            acc[i][j] = (f32x4){0.f, 0.f, 0.f, 0.f};

    for (int kk = 0; kk < K; kk += 32) {
        if (kk) __syncthreads();
        #pragma unroll
        for (int c = 0; c < 2; ++c) {
            const int ch  = w * 2 + c;
            const int row = ch * 16 + lrow;
            const bf16* g = A + (size_t)(bm + row) * K + kk + lk;
            __builtin_amdgcn_global_load_lds(
                (const __attribute__((address_space(1))) unsigned int*)g,
                (__attribute__((address_space(3))) unsigned int*)(As + ch * 512),
                16, 0, 0);
        }
        #pragma unroll
        for (int c = 0; c < 2; ++c) {
            const int ch  = w * 2 + c;
            const int row = ch * 16 + lrow;
            const bf16* g = BT + (size_t)(bn + row) * K + kk + lk;
            __builtin_amdgcn_global_load_lds(
                (const __attribute__((address_space(1))) unsigned int*)g,
                (__attribute__((address_space(3))) unsigned int*)(Bs + ch * 512),
                16, 0, 0);
        }
        __syncthreads();

        s16x8 af[4], bfv[4];
        #pragma unroll
        for (int i = 0; i < 4; ++i)
            af[i] = *(const s16x8*)&As[(wm*64 + i*16 + l16) * 32 + quad*8];
        #pragma unroll
        for (int j = 0; j < 4; ++j)
            bfv[j] = *(const s16x8*)&Bs[(wn*64 + j*16 + l16) * 32 + quad*8];
        #pragma unroll
        for (int i = 0; i < 4; ++i)
            #pragma unroll
            for (int j = 0; j < 4; ++j)
                acc[i][j] = __builtin_amdgcn_mfma_f32_16x16x32_bf16(af[i], bfv[j], acc[i][j], 0, 0, 0);
    }

    #pragma unroll
    for (int i = 0; i < 4; ++i) {
        const int crow = bm + wm*64 + i*16 + quad*4;
        #pragma unroll
        for (int r = 0; r < 4; ++r) {
            #pragma unroll
            for (int j = 0; j < 4; ++j) {
                const int ccol = bn + wn*64 + j*16 + l16;
                if (ccol < N) {
                    const size_t idx = (size_t)(crow + r) * dstride + (ccol - dstoff);
                    if (cf) ((float*)dstp)[idx] = acc[i][j][r];
                    else    ((bf16*)dstp)[idx] = f2b(acc[i][j][r]);
                }
            }
        }
    }
}

// ---------------------------------------------------------------------------
// In-place RMSNorm over rows of X [rows, NPER*256] (internal bf16)
// ---------------------------------------------------------------------------
template<int NPER>
__global__ __launch_bounds__(256) void rms_kernel(bf16* __restrict__ X,
                                                  const void* __restrict__ w,
                                                  const int* __restrict__ flag)
{
    const int wf = *flag;
    const int ncols = NPER * 256;
    __shared__ float red[4];
    const int row = blockIdx.x;
    const int tid = threadIdx.x;
    bf16* xr = X + (size_t)row * ncols;
    float vals[NPER];
    float ss = 0.f;
    #pragma unroll
    for (int i = 0; i < NPER; ++i) {
        float v = b2f(xr[tid + i*256]);
        vals[i] = v; ss += v*v;
    }
    #pragma unroll
    for (int off = 32; off; off >>= 1) ss += __shfl_down(ss, off, 64);
    if ((tid & 63) == 0) red[tid >> 6] = ss;
    __syncthreads();
    const float tot = red[0]+red[1]+red[2]+red[3];
    const float rs  = rsqrtf(tot / (float)ncols + 1e-6f);
    #pragma unroll
    for (int i = 0; i < NPER; ++i) {
        const int c = tid + i*256;
        xr[c] = f2b(vals[i] * rs * ldS(w, c, wf));
    }
}

// ---------------------------------------------------------------------------
// k_pe: in-place RMSNorm over 64 cols + RoPE
// ---------------------------------------------------------------------------
__global__ __launch_bounds__(64) void kpe_rms_rope(bf16* __restrict__ X,
                                                   const void* __restrict__ w,
                                                   const int* __restrict__ flag)
{
    const int wf   = *flag;
    const int row  = blockIdx.x;
    const int t    = row & (T_ - 1);
    const int lane = threadIdx.x;
    bf16* xr = X + (size_t)row * RD_;
    const float v = b2f(xr[lane]);
    float ss = v * v;
    #pragma unroll
    for (int off = 32; off; off >>= 1) ss += __shfl_down(ss, off, 64);
    ss = __shfl(ss, 0, 64);
    const float rs = rsqrtf(ss / 64.f + 1e-6f);
    const float xn = v * rs * ldS(w, lane, wf);
    const int   i  = lane & 31;
    const float freq = powf(10000.f, -(float)(2*i) / 64.f);
    const float ang  = (float)t * freq;
    const float s = sinf(ang), c = cosf(ang);
    const float other = __shfl_xor(xn, 32, 64);
    const float o = (lane < 32) ? (xn * c - other * s) : (other * s + xn * c);
    xr[lane] = f2b(o);
}

// ---------------------------------------------------------------------------
// q_pe RoPE in-place: X [B*T, H*64]
// ---------------------------------------------------------------------------
__global__ __launch_bounds__(256) void qpe_rope(bf16* __restrict__ X)
{
    const int row = blockIdx.x;
    const int t   = row & (T_ - 1);
    bf16* xr = X + (size_t)row * (H_ * RD_);
    const int tid = threadIdx.x;
    #pragma unroll
    for (int pp = 0; pp < 2; ++pp) {
        const int p  = tid + pp * 256;
        const int hh = p >> 5;
        const int i  = p & 31;
        const int i0 = hh * 64 + i;
        const int i1 = i0 + 32;
        const float x1 = b2f(xr[i0]), x2 = b2f(xr[i1]);
        const float freq = powf(10000.f, -(float)(2*i) / 64.f);
        const float ang  = (float)t * freq;
        const float s = sinf(ang), c = cosf(ang);
        xr[i0] = f2b(x1 * c - x2 * s);
        xr[i1] = f2b(x1 * s + x2 * c);
    }
}

// ---------------------------------------------------------------------------
// Flash-style MFMA attention v3 (unchanged from R6, passing @130us).
// ---------------------------------------------------------------------------
__global__ __launch_bounds__(256, 2) void flash_attn(const bf16* __restrict__ qnop,
                                                     const bf16* __restrict__ qpe,
                                                     const bf16* __restrict__ kv,
                                                     const bf16* __restrict__ kpe,
                                                     const bf16* __restrict__ vT,
                                                     bf16* __restrict__ y)
{
    __shared__ __align__(16) short Klds[64][200];   // [krow][dim0..191]
    __shared__ __align__(16) short Vt[128][72];     // [vdim][krow]
    __shared__ __align__(16) short Plds[4][16][72]; // per-wave P [qrow][krow]

    const int h   = blockIdx.x;
    const int qt  = 31 - (int)blockIdx.y;          // heavy blocks dispatched first
    const int b   = blockIdx.z;
    const int q0  = qt * 64;
    const int tid = threadIdx.x;
    const int w    = tid >> 6;
    const int lane = tid & 63;
    const int quad = lane >> 4;
    const int l16  = lane & 15;
    const int row0 = q0 + w * 16;
    const size_t bT = (size_t)b * T_;
    const int bh  = b * H_ + h;

    const int kR = tid >> 4, kC = (tid & 15) * 8;
    const int pR = tid >> 3, pC = (tid & 7) * 8;
    const int vD = tid >> 3, vC = (tid & 7) * 8;

    const bf16* gK = kv  + (bT + kR) * (H_*256) + h*128 + kC;
    const bf16* gP = kpe + (bT + pR) * RD_ + pC;
    const bf16* gV = vT  + ((size_t)bh*HD_ + vD) * T_ + vC;

    s16x8 aq[6];
    {
        const size_t r = bT + row0 + l16;
        const bf16* qn = qnop + r * (H_*128) + h*128 + quad*8;
        #pragma unroll
        for (int kk = 0; kk < 4; ++kk) aq[kk] = *(const s16x8*)(qn + kk*32);
        const bf16* qp = qpe + r * (H_*64) + h*64 + quad*8;
        aq[4] = *(const s16x8*)(qp);
        aq[5] = *(const s16x8*)(qp + 32);
    }

    f32x4 o[8];
    #pragma unroll
    for (int i = 0; i < 8; ++i) o[i] = (f32x4){0.f,0.f,0.f,0.f};
    float m_run[4] = {-1e30f,-1e30f,-1e30f,-1e30f};
    float l_run[4] = {0.f,0.f,0.f,0.f};

    uint4 k0, k1, k2, k3, p0, p1, v0, v1, v2, v3;
    #define PF(J0) do {                                                     \
        const bf16* a_ = gK + (size_t)(J0) * (H_*256);                      \
        k0 = *(const uint4*)(a_);                                           \
        k1 = *(const uint4*)(a_ + 16*(H_*256));                             \
        k2 = *(const uint4*)(a_ + 32*(H_*256));                             \
        k3 = *(const uint4*)(a_ + 48*(H_*256));                             \
        const bf16* p_ = gP + (size_t)(J0) * RD_;                           \
        p0 = *(const uint4*)(p_);                                           \
        p1 = *(const uint4*)(p_ + 32*RD_);                                  \
        const bf16* v_ = gV + (J0);                                         \
        v0 = *(const uint4*)(v_);                                           \
        v1 = *(const uint4*)(v_ + 32*T_);                                   \
        v2 = *(const uint4*)(v_ + 64*T_);                                   \
        v3 = *(const uint4*)(v_ + 96*T_);                                   \
    } while (0)

    PF(0);

    const int ntiles = qt + 1;
    for (int it = 0; it < ntiles; ++it) {
        const int j0 = it * 64;
        asm volatile("s_waitcnt lgkmcnt(0)\n\ts_barrier" ::: "memory");

        *(uint4*)&Klds[kR     ][kC]      = k0;
        *(uint4*)&Klds[kR + 16][kC]      = k1;
        *(uint4*)&Klds[kR + 32][kC]      = k2;
        *(uint4*)&Klds[kR + 48][kC]      = k3;
        *(uint4*)&Klds[pR     ][128+pC]  = p0;
        *(uint4*)&Klds[pR + 32][128+pC]  = p1;
        *(uint4*)&Vt[vD     ][vC]        = v0;
        *(uint4*)&Vt[vD + 32][vC]        = v1;
        *(uint4*)&Vt[vD + 64][vC]        = v2;
        *(uint4*)&Vt[vD + 96][vC]        = v3;

        if (it + 1 < ntiles) PF(j0 + 64);

        asm volatile("s_waitcnt lgkmcnt(0)\n\ts_barrier" ::: "memory");

        if (j0 <= row0 + 15) {
            const bool needmask = (j0 + 63 > row0);
            f32x4 s[4];
            #pragma unroll
            for (int nsub = 0; nsub < 4; ++nsub) {
                f32x4 acc = (f32x4){0.f,0.f,0.f,0.f};
                #pragma unroll
                for (int kk = 0; kk < 6; ++kk) {
                    const s16x8 bk = *(const s16x8*)&Klds[nsub*16 + l16][kk*32 + quad*8];
                    acc = __builtin_amdgcn_mfma_f32_16x16x32_bf16(aq[kk], bk, acc, 0, 0, 0);
                }
                #pragma unroll
                for (int reg = 0; reg < 4; ++reg) acc[reg] *= SCALE_;
                s[nsub] = acc;
            }
            if (needmask) {
                #pragma unroll
                for (int nsub = 0; nsub < 4; ++nsub)
                    #pragma unroll
                    for (int reg = 0; reg < 4; ++reg) {
                        const int col = j0 + nsub*16 + l16;
                        const int row = row0 + quad*4 + reg;
                        if (col > row) s[nsub][reg] = -1e30f;
                    }
            }
            float mt[4], alpha[4], rs[4];
            #pragma unroll
            for (int reg = 0; reg < 4; ++reg)
                mt[reg] = fmaxf(fmaxf(s[0][reg], s[1][reg]), fmaxf(s[2][reg], s[3][reg]));
            #pragma unroll
            for (int d = 1; d < 16; d <<= 1)
                #pragma unroll
                for (int reg = 0; reg < 4; ++reg)
                    mt[reg] = fmaxf(mt[reg], __shfl_xor(mt[reg], d, 64));
            #pragma unroll
            for (int reg = 0; reg < 4; ++reg) {
                const float mnew = fmaxf(m_run[reg], mt[reg]);
                alpha[reg] = __expf(m_run[reg] - mnew);
                m_run[reg] = mnew;
                rs[reg] = 0.f;
            }
            #pragma unroll
            for (int nsub = 0; nsub < 4; ++nsub)
                #pragma unroll
                for (int reg = 0; reg < 4; ++reg) {
                    const float p = __expf(s[nsub][reg] - m_run[reg]);
                    s[nsub][reg] = p;
                    rs[reg] += p;
                }
            #pragma unroll
            for (int d = 1; d < 16; d <<= 1)
                #pragma unroll
                for (int reg = 0; reg < 4; ++reg)
                    rs[reg] += __shfl_xor(rs[reg], d, 64);
            #pragma unroll
            for (int reg = 0; reg < 4; ++reg)
                l_run[reg] = l_run[reg] * alpha[reg] + rs[reg];

            #pragma unroll
            for (int nsub = 0; nsub < 4; ++nsub)
                #pragma unroll
                for (int reg = 0; reg < 4; ++reg) {
                    const bf16 pv = f2b(s[nsub][reg]);
                    Plds[w][quad*4 + reg][nsub*16 + l16] = *(const short*)&pv;
                }
            #pragma unroll
            for (int n2 = 0; n2 < 8; ++n2)
                #pragma unroll
                for (int reg = 0; reg < 4; ++reg)
                    o[n2][reg] *= alpha[reg];

            const s16x8 ap0 = *(const s16x8*)&Plds[w][l16][quad*8];
            const s16x8 ap1 = *(const s16x8*)&Plds[w][l16][32 + quad*8];
            #pragma unroll
            for (int n2 = 0; n2 < 8; ++n2) {
                const s16x8 bv0 = *(const s16x8*)&Vt[n2*16 + l16][quad*8];
                const s16x8 bv1 = *(const s16x8*)&Vt[n2*16 + l16][32 + quad*8];
                o[n2] = __builtin_amdgcn_mfma_f32_16x16x32_bf16(ap0, bv0, o[n2], 0, 0, 0);
                o[n2] = __builtin_amdgcn_mfma_f32_16x16x32_bf16(ap1, bv1, o[n2], 0, 0, 0);
            }
        }
    }
    #undef PF

    #pragma unroll
    for (int reg = 0; reg < 4; ++reg) {
        const float inv = 1.f / l_run[reg];
        const size_t r = bT + row0 + quad*4 + reg;
        bf16* yr = y + r * (H_*128) + h*128 + l16;
        #pragma unroll
        for (int n2 = 0; n2 < 8; ++n2)
            yr[n2*16] = f2b(o[n2][reg] * inv);
    }
}

// ---------------------------------------------------------------------------
extern "C" void kernel_launch(void* const* d_in, const int* in_sizes, int n_in,
                              void* d_out, int out_size, void* d_ws, size_t ws_size,
                              hipStream_t stream)
{
    const void* x         = d_in[0];
    const void* Wq_down   = d_in[1];
    const void* q_norm_w  = d_in[2];
    const void* Wq_up     = d_in[3];
    const void* Wq_pe     = d_in[4];
    const void* Wkv_down  = d_in[5];
    const void* kv_norm_w = d_in[6];
    const void* Wkv_up    = d_in[7];
    const void* Wk_pe     = d_in[8];
    const void* kpe_nw    = d_in[9];
    const void* Wo        = d_in[10];

    char* ws = (char*)d_ws;
    int*  flag = (int*)(ws + 0);
    bf16* xb   = (bf16*)(ws + 256);        // [4096,2048] — dead after x-GEMM; reused as vT
    bf16* cQ   = (bf16*)(ws + 16777472);   // [4096,1536] — dead after q-GEMM; reused as P3/P4
    bf16* cKV  = (bf16*)(ws + 29360384);   // [4096, 512]
    bf16* kpeb = (bf16*)(ws + 33554688);   // [4096,  64]
    bf16* qnop = (bf16*)(ws + 34078976);   // [4096,2048]
    bf16* qpeb = (bf16*)(ws + 50856192);   // [4096,1024]
    bf16* kvb  = (bf16*)(ws + 59244800);   // [4096,4096] — written late; holds P1/P2 early
    bf16* yb   = (bf16*)(ws + 92799232);   // [4096,2048]  (end 109,576,448)

    // weight arenas (lifetime-safe overlays):
    bf16* P1 = kvb;                            // [2176][2048] x-weights^T (8.9 MB)
    bf16* P2 = (bf16*)((char*)kvb + 8912896);  // [3072][1536] q-weights^T (9.4 MB)
    bf16* P3 = cQ;                             // [4096][512]  Wkv_up^T    (4.2 MB)
    bf16* P4 = (bf16*)((char*)cQ + 4194304);   // [2048][2048] Wo^T        (8.4 MB)
    bf16* vT = xb;                             // [B*H][128][2048] V^T

    const dim3 blk(256);

    detect_kernel<<<1, dim3(64), 0, stream>>>((const unsigned short*)x, flag);
    convert_kernel<<<(B_*T_*C_)/(256*8), blk, 0, stream>>>(x, xb, B_*T_*C_, flag);

    // ---- batched transpose #1: x-path + q-path weights ----
    {
        TBatch tb;
        tb.d[0] = { Wq_down,  P1,               C_,  QLR_,     0, QLR_/32 };    // 3072 blks
        tb.d[1] = { Wkv_down, P1 + 1536*2048,   C_,  KLR_,  3072, KLR_/32 };    // 1024
        tb.d[2] = { Wk_pe,    P1 + 2048*2048,   C_,  RD_,   4096, RD_/32  };    //  128
        tb.d[3] = { Wq_up,    P2,               QLR_, 2048, 4224, 2048/32 };    // 3072
        tb.d[4] = { Wq_pe,    P2 + 2048*1536,   QLR_, 1024, 7296, 1024/32 };    // 1536
        tb.nseg = 5;
        transpose_batch<<<8832, blk, 0, stream>>>(tb, flag);
    }

    // ---- fused x-projection GEMM: x @ [Wq_down | Wkv_down | Wk_pe] ----
    {
        GOuts go; go.nseg = 3;
        go.p[0]=cQ;   go.start[0]=0;    go.stride[0]=QLR_;
        go.p[1]=cKV;  go.start[1]=1536; go.stride[1]=KLR_;
        go.p[2]=kpeb; go.start[2]=2048; go.stride[2]=RD_;
        mfma_gemm<<<dim3(17, 32), blk, 0, stream>>>(xb, P1, go, 2112, C_, flag, 0);
    }
    rms_kernel<6><<<B_*T_, blk, 0, stream>>>(cQ, q_norm_w, flag);
    rms_kernel<2><<<B_*T_, blk, 0, stream>>>(cKV, kv_norm_w, flag);
    kpe_rms_rope<<<B_*T_, dim3(64), 0, stream>>>(kpeb, kpe_nw, flag);

    // ---- fused q-projection GEMM: cQ @ [Wq_up | Wq_pe] ----
    {
        GOuts go; go.nseg = 2;
        go.p[0]=qnop; go.start[0]=0;    go.stride[0]=H_*HD_;
        go.p[1]=qpeb; go.start[1]=2048; go.stride[1]=H_*RD_;
        go.p[2]=nullptr; go.start[2]=0; go.stride[2]=0;
        mfma_gemm<<<dim3(24, 32), blk, 0, stream>>>(cQ, P2, go, 3072, QLR_, flag, 0);
    }
    qpe_rope<<<B_*T_, blk, 0, stream>>>(qpeb);

    // ---- batched transpose #2: Wkv_up, Wo (cQ now dead) ----
    {
        TBatch tb;
        tb.d[0] = { Wkv_up, P3, KLR_, H_*2*HD_,    0, (H_*2*HD_)/32 };  // 2048 blks
        tb.d[1] = { Wo,     P4, H_*HD_, C_,     2048, C_/32 };          // 4096
        tb.d[2] = tb.d[1]; tb.d[3] = tb.d[1]; tb.d[4] = tb.d[1];
        tb.nseg = 2;
        transpose_batch<<<6144, blk, 0, stream>>>(tb, flag);
    }

    // ---- kv up-projection, then V transpose (xb dead) ----
    {
        GOuts go; go.nseg = 1;
        go.p[0]=kvb; go.start[0]=0; go.stride[0]=H_*2*HD_;
        go.p[1]=nullptr; go.start[1]=0; go.stride[1]=0;
        go.p[2]=nullptr; go.start[2]=0; go.stride[2]=0;
        mfma_gemm<<<dim3(32, 32), blk, 0, stream>>>(cKV, P3, go, H_*2*HD_, KLR_, flag, 0);
    }
    transpose_v_kernel<<<dim3((H_*HD_)/32, (B_*T_)/32), blk, 0, stream>>>(kvb, vT);

    // ---- attention ----
    flash_attn<<<dim3(H_, T_/64, B_), blk, 0, stream>>>(qnop, qpeb, kvb, kpeb, vT, yb);

    // ---- output projection (dtype of d_out per flag) ----
    {
        GOuts go; go.nseg = 1;
        go.p[0]=d_out; go.start[0]=0; go.stride[0]=C_;
        go.p[1]=nullptr; go.start[1]=0; go.stride[1]=0;
        go.p[2]=nullptr; go.start[2]=0; go.stride[2]=0;
        mfma_gemm<<<dim3(C_/128, 32), blk, 0, stream>>>(yb, P4, go, C_, H_*HD_, flag, 1);
    }
}